// Round 3
// baseline (149.766 us; speedup 1.0000x reference)
//
#include <hip/hip_runtime.h>

// Fused MLPKAN, round 7 (resubmit — round-2 bench was an infra failure:
// "MI355X container failed twice"; no counters returned).
// Post-mortem r6: wave-uniform GLOBAL x loads (xT) were serialized by the
// compiler (VGPR=52 => loads sunk into j-loop, vmcnt waits each chunk);
// VALUBusy 27%, kernel 71us. Fix: revert x path to LDS staging + ds_read_b128
// broadcasts (round-5's proven path), KEEP the r6 wins:
//   - 8 waves = 8 i-groups of 8: ONE weight copy per block (r5 had 2).
//   - h accumulated straight into ht[64][34] via ds_add_f32; no hp buffer,
//     no transpose pass, one barrier fewer. (o,j)->bank is 2-way = free.
// Register discipline: j-loop split into 2x16 halves (xv[4] live, not xv[8]);
// layer-1 processes its two i's with both weight sets hoisted.
// Target VGPR ~90 (<=128 for 4 waves/SIMD), LDS ~20KB, grid 512 = 2 blk/CU.

typedef float v2f __attribute__((ext_vector_type(2)));

#define BATCH 16384
#define TB    32

__global__ __launch_bounds__(512, 4) void kan_fused3(
    const float* __restrict__ x,
    const float* __restrict__ A1, const float* __restrict__ a1,
    const float* __restrict__ A2, const float* __restrict__ a2,
    const float* __restrict__ A3, const float* __restrict__ a3,
    const float* __restrict__ B1, const float* __restrict__ c1,
    const float* __restrict__ B2, const float* __restrict__ c2,
    const float* __restrict__ B3, const float* __restrict__ c3,
    float* __restrict__ out)
{
    __shared__ float xs[64][36];   // x transposed: xs[i][b]; rows 144B (16B-aligned)
    __shared__ float ht[64][34];   // h transposed, ds_add accumulated; rows 136B (8B-aligned)
    __shared__ float op[TB][16];   // layer1 output accum

    const int t    = threadIdx.x;
    const int lane = t & 63;
    const int w    = t >> 6;       // 0..7 = i-group
    const int bB0  = blockIdx.x * TB;

    // zero LDS accumulators (before first barrier; used after it)
    {
        float* hb = &ht[0][0];
        for (int k = t; k < 64 * 34; k += 512) hb[k] = 0.f;
        (&op[0][0])[t] = 0.f;      // TB*16 == 512
    }

    // ---- stage x transposed: 2048 floats, 512 thr x float4 ----
    {
        const int k = t * 4;
        const float4 v = *(const float4*)(x + (long)bB0 * 64 + k);
        const int b = k >> 6, i = k & 63;
        xs[i][b] = v.x; xs[i + 1][b] = v.y; xs[i + 2][b] = v.z; xs[i + 3][b] = v.w;
    }
    __syncthreads();

    const v2f zz = {0.f, 0.f};

    // ================= layer 0: 64 -> 64, wave = 8 i's, lane = o =================
    {
        const int o  = lane;
        const int i0 = 8 * w;

        auto ldw = [&](int i, v2f& w1, v2f& d1, float4& w2, v2f& d2, v2f& w3, float& b3v) {
            const int n = (i << 6) + o;
            w1  = *(const v2f*)(A1 + 2 * n);
            d1  = *(const v2f*)(a1 + 2 * n);
            w2  = *(const float4*)(A2 + 4 * n);
            d2  = *(const v2f*)(a2 + 2 * n);
            w3  = *(const v2f*)(A3 + 2 * n);
            b3v = a3[n];
        };

        float acc[TB];
#pragma unroll
        for (int j = 0; j < TB; ++j) acc[j] = 0.f;
        float bsum = 0.f;

        v2f w1, d1, d2, w3; float4 w2; float b3v;
        ldw(i0, w1, d1, w2, d2, w3, b3v);

#pragma unroll 1
        for (int ii = 0; ii < 8; ++ii) {
            const int i = i0 + ii;
            v2f nw1, nd1, nd2, nw3; float4 nw2; float nb3;
            ldw(i0 + ((ii + 1) & 7), nw1, nd1, nw2, nd2, nw3, nb3);  // in flight

            bsum += b3v;
            const v2f c0  = {w2.x, w2.z};
            const v2f c1v = {w2.y, w2.w};

#pragma unroll
            for (int half = 0; half < 2; ++half) {
                float4 xv[4];                       // ds b128 broadcasts (wave-uniform)
#pragma unroll
                for (int q = 0; q < 4; ++q)
                    xv[q] = *(const float4*)&xs[i][16 * half + 4 * q];
#pragma unroll
                for (int jj = 0; jj < 16; ++jj) {
                    const int j = 16 * half + jj;
                    const float xb = ((const float*)xv)[jj];
                    const v2f xd = {xb, xb};
                    v2f m = __builtin_elementwise_fma(xd, w1, d1);
                    m = __builtin_elementwise_max(m, zz);
                    const v2f mm0 = {m.x, m.x};
                    const v2f mm1 = {m.y, m.y};
                    v2f tt = __builtin_elementwise_fma(c1v, mm1, d2);
                    tt = __builtin_elementwise_fma(c0, mm0, tt);
                    tt = __builtin_elementwise_max(tt, zz);
                    acc[j] = fmaf(w3.x, tt.x, fmaf(w3.y, tt.y, acc[j]));
                }
            }
            w1 = nw1; d1 = nd1; w2 = nw2; d2 = nd2; w3 = nw3; b3v = nb3;
        }

        // accumulate: bank=(2o+j)%32 -> 2-way alias (free); 8 waves/address over time
#pragma unroll
        for (int j = 0; j < TB; ++j)
            atomicAdd(&ht[o][j], acc[j] + bsum);
    }
    __syncthreads();

    // ================= layer 1: 64 -> 16, lane = (ig, o1), wave = 8 i's =========
    {
        const int o1 = lane & 15;
        const int ig = lane >> 4;              // 4 groups x 2 i's

        float acc[TB];
#pragma unroll
        for (int j = 0; j < TB; ++j) acc[j] = 0.f;
        float bsum = 0.f;

        const int iA = 8 * w + 2 * ig;
        const int iB = iA + 1;

        auto ldw = [&](int i, v2f& w1, v2f& d1, float4& w2, v2f& d2, v2f& w3) {
            const int n = (i << 4) + o1;
            w1  = *(const v2f*)(B1 + 2 * n);
            d1  = *(const v2f*)(c1 + 2 * n);
            w2  = *(const float4*)(B2 + 4 * n);
            d2  = *(const v2f*)(c2 + 2 * n);
            w3  = *(const v2f*)(B3 + 2 * n);
        };

        auto body = [&](int i, const v2f& w1, const v2f& d1, const float4& w2,
                        const v2f& d2, const v2f& w3) {
            const v2f c0  = {w2.x, w2.z};
            const v2f c1v = {w2.y, w2.w};
            // ht row reads: 4 distinct b64 addrs/wave, banks 4 apart -> conflict-free
#pragma unroll
            for (int half = 0; half < 2; ++half) {
                v2f hv[8];
#pragma unroll
                for (int q = 0; q < 8; ++q)
                    hv[q] = *(const v2f*)&ht[i][16 * half + 2 * q];
#pragma unroll
                for (int jj = 0; jj < 16; ++jj) {
                    const int j = 16 * half + jj;
                    const float hb = ((const float*)hv)[jj];
                    const v2f xd = {hb, hb};
                    v2f m = __builtin_elementwise_fma(xd, w1, d1);
                    m = __builtin_elementwise_max(m, zz);
                    const v2f mm0 = {m.x, m.x};
                    const v2f mm1 = {m.y, m.y};
                    v2f tt = __builtin_elementwise_fma(c1v, mm1, d2);
                    tt = __builtin_elementwise_fma(c0, mm0, tt);
                    tt = __builtin_elementwise_max(tt, zz);
                    acc[j] = fmaf(w3.x, tt.x, fmaf(w3.y, tt.y, acc[j]));
                }
            }
        };

        v2f w1A, d1A, d2A, w3A; float4 w2A;
        v2f w1B, d1B, d2B, w3B; float4 w2B;
        ldw(iA, w1A, d1A, w2A, d2A, w3A);
        ldw(iB, w1B, d1B, w2B, d2B, w3B);
        bsum = c3[(iA << 4) + o1] + c3[(iB << 4) + o1];

        body(iA, w1A, d1A, w2A, d2A, w3A);
        body(iB, w1B, d1B, w2B, d2B, w3B);

        // reduce over ig (lanes 16 apart), then ds_add across waves
#pragma unroll
        for (int j = 0; j < TB; ++j) {
            float v = acc[j] + bsum;
            v += __shfl_xor(v, 16, 64);
            v += __shfl_xor(v, 32, 64);
            if (ig == 0) atomicAdd(&op[j][o1], v);   // 16 consecutive banks, clean
        }
    }
    __syncthreads();

    // ---- store: 512 floats, float4 coalesced ----
    if (t < 128) {
        const float4 r = *(const float4*)(&op[0][0] + t * 4);
        *(float4*)(out + (long)bB0 * 16 + t * 4) = r;
    }
}

extern "C" void kernel_launch(void* const* d_in, const int* in_sizes, int n_in,
                              void* d_out, int out_size, void* d_ws, size_t ws_size,
                              hipStream_t stream) {
    const float* x     = (const float*)d_in[0];
    const float* l0_W1 = (const float*)d_in[1];
    const float* l0_b1 = (const float*)d_in[2];
    const float* l0_W2 = (const float*)d_in[3];
    const float* l0_b2 = (const float*)d_in[4];
    const float* l0_W3 = (const float*)d_in[5];
    const float* l0_b3 = (const float*)d_in[6];
    const float* l1_W1 = (const float*)d_in[7];
    const float* l1_b1 = (const float*)d_in[8];
    const float* l1_W2 = (const float*)d_in[9];
    const float* l1_b2 = (const float*)d_in[10];
    const float* l1_W3 = (const float*)d_in[11];
    const float* l1_b3 = (const float*)d_in[12];

    float* outp = (float*)d_out;

    dim3 blk(512);
    dim3 grid(BATCH / TB);   // 512 blocks, 2 per CU, 4 waves/SIMD

    hipLaunchKernelGGL(kan_fused3, grid, blk, 0, stream,
                       x,
                       l0_W1, l0_b1, l0_W2, l0_b2, l0_W3, l0_b3,
                       l1_W1, l1_b1, l1_W2, l1_b2, l1_W3, l1_b3,
                       outp);
}

// Round 5
// 143.673 us; speedup vs baseline: 1.0424x; 1.0424x over previous
//
#include <hip/hip_runtime.h>

// Fused MLPKAN, round 10 — consolidation on proven pieces only.
// r9 post-mortem: SMEM s_load inline-asm ping-pong corrupted data (missing
// early-clobber => output quads may alias the base-pointer pair; async write
// clobbers the pointer mid-sequence). SMEM path abandoned.
// This round = r5 wave structure (iq x bh, acc[16], proven codegen) +
// r7-proven LDS mechanisms + mov-free 1-deep double-buffer prefetch:
//   - layer0 partial sums go straight into ht[64][34] via ds_add_f32
//     (atomicAdd on LDS): hp buffer (32KB) gone, combine pass gone, one
//     barrier gone. Bank = (2o+j)%32 -> 2-way = free (m136).
//   - layer1 partials via atomicAdd into op[32][16] (16 lanes, 16 banks).
//   - i-loop unrolled x2 with A/B register buffers for BOTH weights (global)
//     and x/h tiles (LDS b128/b64): next-i loads issued before current-i
//     compute, no rotation movs; compiler emits counted lgkmcnt/vmcnt.
// LDS 20KB (xs 9216 + ht 8704 + op 2048). Grid 512 = 2 blk/CU, 4 waves/SIMD.
// ht stride 34 => layer1 reads are v2f (b64), 8B-aligned (136*i + 8q).

typedef float v2f __attribute__((ext_vector_type(2)));

#define BATCH 16384
#define TB    32

struct Wt { v2f w1, d1; float4 w2; v2f d2, w3; float b3; };

__global__ __launch_bounds__(512, 4) void kan_fused5(
    const float* __restrict__ x,
    const float* __restrict__ A1, const float* __restrict__ a1,
    const float* __restrict__ A2, const float* __restrict__ a2,
    const float* __restrict__ A3, const float* __restrict__ a3,
    const float* __restrict__ B1, const float* __restrict__ c1,
    const float* __restrict__ B2, const float* __restrict__ c2,
    const float* __restrict__ B3, const float* __restrict__ c3,
    float* __restrict__ out)
{
    __shared__ float xs[64][36];   // x transposed: xs[i][b]; rows 144B, 16B-aligned
    __shared__ float ht[64][34];   // h transposed, ds_add-accumulated
    __shared__ float op[TB][16];   // layer1 output accum

    const int t    = threadIdx.x;
    const int lane = t & 63;
    const int wave = t >> 6;            // 0..7
    const int iq   = wave & 3;          // i-quarter: [16*iq, 16*iq+16)
    const int bh   = wave >> 2;         // batch-half: [16*bh, 16*bh+16)
    const int bB0  = blockIdx.x * TB;
    const int boff = 16 * bh;

    // ---- zero LDS accumulators + stage x transposed (same pre-barrier phase) ----
    {
        float* hb = &ht[0][0];
        for (int k = t; k < 64 * 34; k += 512) hb[k] = 0.f;
        (&op[0][0])[t] = 0.f;           // TB*16 == 512

        const int k = t * 4;
        const float4 v = *(const float4*)(x + (long)bB0 * 64 + k);
        const int b = k >> 6, i = k & 63;
        xs[i][b] = v.x; xs[i + 1][b] = v.y; xs[i + 2][b] = v.z; xs[i + 3][b] = v.w;
    }
    __syncthreads();

    const v2f zz = {0.f, 0.f};

    // ================= layer 0: 64 -> 64 =================
    {
        const int o  = lane;
        const int i0 = 16 * iq;

        auto ldw = [&](int i) {
            Wt W; const int n = (i << 6) + o;
            W.w1 = *(const v2f*)(A1 + 2 * n);
            W.d1 = *(const v2f*)(a1 + 2 * n);
            W.w2 = *(const float4*)(A2 + 4 * n);
            W.d2 = *(const v2f*)(a2 + 2 * n);
            W.w3 = *(const v2f*)(A3 + 2 * n);
            W.b3 = a3[n];
            return W;
        };
        auto ldx = [&](int i, float4* xv) {
#pragma unroll
            for (int q = 0; q < 4; ++q)
                xv[q] = *(const float4*)&xs[i][boff + 4 * q];   // uniform b128
        };

        float acc[16];
#pragma unroll
        for (int j = 0; j < 16; ++j) acc[j] = 0.f;
        float bsum = 0.f;

        auto comp = [&](const Wt& W, const float4* xv) {
            bsum += W.b3;
            const v2f c0  = {W.w2.x, W.w2.z};
            const v2f c1v = {W.w2.y, W.w2.w};
#pragma unroll
            for (int j = 0; j < 16; ++j) {
                const float xb = ((const float*)xv)[j];
                const v2f xd = {xb, xb};
                v2f m = __builtin_elementwise_fma(xd, W.w1, W.d1);
                m = __builtin_elementwise_max(m, zz);
                const v2f mm0 = {m.x, m.x};
                const v2f mm1 = {m.y, m.y};
                v2f tt = __builtin_elementwise_fma(c1v, mm1, W.d2);
                tt = __builtin_elementwise_fma(c0, mm0, tt);
                tt = __builtin_elementwise_max(tt, zz);
                acc[j] = fmaf(W.w3.x, tt.x, fmaf(W.w3.y, tt.y, acc[j]));
            }
        };

        Wt WA = ldw(i0), WB;
        float4 XA[4], XB[4];
        ldx(i0, XA);

#pragma unroll 1
        for (int ii = 0; ii < 16; ii += 2) {
            WB = ldw(i0 + ((ii + 1) & 15));       // next weights in flight
            ldx(i0 + ((ii + 1) & 15), XB);        // next x-tile in flight
            comp(WA, XA);
            WA = ldw(i0 + ((ii + 2) & 15));       // wraps to i0 at ii=14 (dead)
            ldx(i0 + ((ii + 2) & 15), XA);
            comp(WB, XB);
        }

        // accumulate into ht: bank=(2o+boff+j)%32 -> 2-way alias, free
#pragma unroll
        for (int j = 0; j < 16; ++j)
            atomicAdd(&ht[o][boff + j], acc[j] + bsum);
    }
    __syncthreads();

    // ================= layer 1: 64 -> 16 =================
    {
        const int o1 = lane & 15;
        const int ig = lane >> 4;          // 4 i-subgroups of 4
        const int i0 = 16 * iq + 4 * ig;

        auto ldw = [&](int i) {
            Wt W; const int n = (i << 4) + o1;
            W.w1 = *(const v2f*)(B1 + 2 * n);
            W.d1 = *(const v2f*)(c1 + 2 * n);
            W.w2 = *(const float4*)(B2 + 4 * n);
            W.d2 = *(const v2f*)(c2 + 2 * n);
            W.w3 = *(const v2f*)(B3 + 2 * n);
            W.b3 = c3[n];
            return W;
        };
        auto ldh = [&](int i, v2f* hv) {
#pragma unroll
            for (int q = 0; q < 8; ++q)
                hv[q] = *(const v2f*)&ht[i][boff + 2 * q];   // uniform b64, aligned
        };

        float acc[16];
#pragma unroll
        for (int j = 0; j < 16; ++j) acc[j] = 0.f;
        float bsum = 0.f;

        auto comp = [&](const Wt& W, const v2f* hv) {
            bsum += W.b3;
            const v2f c0  = {W.w2.x, W.w2.z};
            const v2f c1v = {W.w2.y, W.w2.w};
#pragma unroll
            for (int j = 0; j < 16; ++j) {
                const float hb = ((const float*)hv)[j];
                const v2f xd = {hb, hb};
                v2f m = __builtin_elementwise_fma(xd, W.w1, W.d1);
                m = __builtin_elementwise_max(m, zz);
                const v2f mm0 = {m.x, m.x};
                const v2f mm1 = {m.y, m.y};
                v2f tt = __builtin_elementwise_fma(c1v, mm1, W.d2);
                tt = __builtin_elementwise_fma(c0, mm0, tt);
                tt = __builtin_elementwise_max(tt, zz);
                acc[j] = fmaf(W.w3.x, tt.x, fmaf(W.w3.y, tt.y, acc[j]));
            }
        };

        Wt WA = ldw(i0), WB;
        v2f HA[8], HB[8];
        ldh(i0, HA);

#pragma unroll 1
        for (int ii = 0; ii < 4; ii += 2) {
            WB = ldw(i0 + ((ii + 1) & 3));
            ldh(i0 + ((ii + 1) & 3), HB);
            comp(WA, HA);
            WA = ldw(i0 + ((ii + 2) & 3));
            ldh(i0 + ((ii + 2) & 3), HA);
            comp(WB, HB);
        }

        // reduce over ig (lanes 16 apart), atomic-add the iq partial
#pragma unroll
        for (int j = 0; j < 16; ++j) {
            float v = acc[j] + bsum;
            v += __shfl_xor(v, 16, 64);
            v += __shfl_xor(v, 32, 64);
            if (ig == 0) atomicAdd(&op[boff + j][o1], v);   // 16 lanes, 16 banks
        }
    }
    __syncthreads();

    // ---- store: 512 floats, float4 coalesced ----
    if (t < 128) {
        const float4 r = *(const float4*)(&op[0][0] + t * 4);
        *(float4*)(out + (long)bB0 * 16 + t * 4) = r;
    }
}

extern "C" void kernel_launch(void* const* d_in, const int* in_sizes, int n_in,
                              void* d_out, int out_size, void* d_ws, size_t ws_size,
                              hipStream_t stream) {
    const float* x     = (const float*)d_in[0];
    const float* l0_W1 = (const float*)d_in[1];
    const float* l0_b1 = (const float*)d_in[2];
    const float* l0_W2 = (const float*)d_in[3];
    const float* l0_b2 = (const float*)d_in[4];
    const float* l0_W3 = (const float*)d_in[5];
    const float* l0_b3 = (const float*)d_in[6];
    const float* l1_W1 = (const float*)d_in[7];
    const float* l1_b1 = (const float*)d_in[8];
    const float* l1_W2 = (const float*)d_in[9];
    const float* l1_b2 = (const float*)d_in[10];
    const float* l1_W3 = (const float*)d_in[11];
    const float* l1_b3 = (const float*)d_in[12];

    float* outp = (float*)d_out;

    dim3 blk(512);
    dim3 grid(BATCH / TB);   // 512 blocks, 2 per CU

    hipLaunchKernelGGL(kan_fused5, grid, blk, 0, stream,
                       x,
                       l0_W1, l0_b1, l0_W2, l0_b2, l0_W3, l0_b3,
                       l1_W1, l1_b1, l1_W2, l1_b2, l1_W3, l1_b3,
                       outp);
}

// Round 7
// 140.663 us; speedup vs baseline: 1.0647x; 1.0214x over previous
//
#include <hip/hip_runtime.h>

// Fused MLPKAN, round 11 RESUBMIT (round-6 bench was an infra failure:
// "MI355X container failed twice"; no signal returned).
// INSTRUMENTED ABLATION on the r0 (proven 34us) base.
// r6/r7/r10 post-mortem: three different restructures (global-x, LDS-x+atomics,
// double-buffered) all land at the same ~19.5us VALU-issue time but 71-81us
// total; r0's kernel has never been profiled (hides under the 40us harness
// fills). This round buys counters:
//   - r0 structure VERBATIM (iq x bh waves, acc per 16 b, hp partials,
//     combine pass, op partials — no LDS atomics, no zero-init).
//   - pk-accumulators: acc2[j] = v_pk_fma(w3, tt, acc2[j]) replaces the
//     2x scalar fmaf tail (7 -> 6 inner VALU), horizontal add at write-out.
//   - REPEAT=3 on the layer0 i-loop: asm keep-alives prevent DCE of reps 1-2,
//     per-rep "memory" clobber prevents weight/xs load CSE. Kernel ~60-70us
//     => visible in rocprof top-5 with layer0-dominated counters.
// Readout: marginal L0 = (dur_us - 103)/2; VALUBusy >=50% => VALU-bound
// (next: trim addressing), <=40% => stall-bound (next: latency/occupancy).

typedef float v2f __attribute__((ext_vector_type(2)));

#define BATCH  16384
#define TB     32
#define REPEAT 3

__global__ __launch_bounds__(512, 4) void kan_fused6(
    const float* __restrict__ x,
    const float* __restrict__ A1, const float* __restrict__ a1,
    const float* __restrict__ A2, const float* __restrict__ a2,
    const float* __restrict__ A3, const float* __restrict__ a3,
    const float* __restrict__ B1, const float* __restrict__ c1,
    const float* __restrict__ B2, const float* __restrict__ c2,
    const float* __restrict__ B3, const float* __restrict__ c3,
    float* __restrict__ out)
{
    __shared__ float xs[64][36];        // x transposed: xs[i][b]
    __shared__ float hp[4][TB][64];     // layer0 partials per i-quarter
    __shared__ float ht[64][36];        // h transposed: ht[i][b]
    __shared__ float op[4][TB][16];     // layer1 partials per i-quarter

    const int t    = threadIdx.x;
    const int lane = t & 63;
    const int wave = t >> 6;            // 0..7
    const int iq   = wave & 3;          // i-quarter: [16*iq, 16*iq+16)
    const int bh   = wave >> 2;         // batch-half: [16*bh, 16*bh+16)
    const int bB0  = blockIdx.x * TB;

    // ---- stage x transposed: 2048 floats, 512 thr x float4 ----
    {
        const int k = t * 4;
        const float4 v = *(const float4*)(x + (long)bB0 * 64 + k);
        const int b = k >> 6, i = k & 63;
        xs[i][b] = v.x; xs[i + 1][b] = v.y; xs[i + 2][b] = v.z; xs[i + 3][b] = v.w;
    }
    __syncthreads();

    const v2f zz = {0.f, 0.f};
    const int boff = 16 * bh;

    // ================= layer 0: 64 -> 64 =================
    {
        const int o  = lane;
        const int i0 = 16 * iq;

        auto ldw = [&](int i, v2f& w1, v2f& d1, float4& w2, v2f& d2, v2f& w3, float& b3v) {
            const int n = (i << 6) + o;
            w1  = *(const v2f*)(A1 + 2 * n);
            d1  = *(const v2f*)(a1 + 2 * n);
            w2  = *(const float4*)(A2 + 4 * n);
            d2  = *(const v2f*)(a2 + 2 * n);
            w3  = *(const v2f*)(A3 + 2 * n);
            b3v = a3[n];
        };

        v2f acc2[16];
        float bsum = 0.f;

#pragma unroll 1
        for (int rep = 0; rep < REPEAT; ++rep) {
            // anti-CSE: force reloads of weights/xs each rep (instrumentation)
            asm volatile("" ::: "memory");
#pragma unroll
            for (int j = 0; j < 16; ++j) acc2[j] = zz;
            bsum = 0.f;

            v2f w1, d1, d2, w3; float4 w2; float b3v;
            ldw(i0, w1, d1, w2, d2, w3, b3v);

#pragma unroll 1
            for (int ii = 0; ii < 16; ++ii) {
                const int i = i0 + ii;
                v2f nw1, nd1, nd2, nw3; float4 nw2; float nb3;
                ldw(i0 + ((ii + 1) & 15), nw1, nd1, nw2, nd2, nw3, nb3);  // in flight

                const float4 xv0 = *(const float4*)&xs[i][boff];          // ds b128
                const float4 xv1 = *(const float4*)&xs[i][boff + 4];
                const float4 xv2 = *(const float4*)&xs[i][boff + 8];
                const float4 xv3 = *(const float4*)&xs[i][boff + 12];
                const float4 xv[4] = {xv0, xv1, xv2, xv3};

                bsum += b3v;
                const v2f c0  = {w2.x, w2.z};
                const v2f c1v = {w2.y, w2.w};
#pragma unroll
                for (int j = 0; j < 16; ++j) {
                    const float xb = ((const float*)xv)[j];
                    const v2f xd = {xb, xb};
                    v2f m = __builtin_elementwise_fma(xd, w1, d1);
                    m = __builtin_elementwise_max(m, zz);
                    const v2f mm0 = {m.x, m.x};
                    const v2f mm1 = {m.y, m.y};
                    v2f tt = __builtin_elementwise_fma(c1v, mm1, d2);
                    tt = __builtin_elementwise_fma(c0, mm0, tt);
                    tt = __builtin_elementwise_max(tt, zz);
                    acc2[j] = __builtin_elementwise_fma(w3, tt, acc2[j]);  // pk fma
                }
                w1 = nw1; d1 = nd1; w2 = nw2; d2 = nd2; w3 = nw3; b3v = nb3;
            }

            if (rep != REPEAT - 1) {
                // keep rep's results live (anti-DCE), then reset
#pragma unroll
                for (int j = 0; j < 16; ++j)
                    asm volatile("" : "+v"(acc2[j]));
                asm volatile("" : "+v"(bsum));
            }
        }

#pragma unroll
        for (int j = 0; j < 16; ++j)
            hp[iq][boff + j][o] = acc2[j].x + acc2[j].y + bsum;  // 2-way, free
    }
    __syncthreads();

    // ---- combine i-quarters + transpose: ht[i][b] = sum_q hp[q][b][i] ----
    for (int k = t; k < TB * 64; k += 512) {
        const int b = k >> 6, i = k & 63;
        ht[i][b] = hp[0][b][i] + hp[1][b][i] + hp[2][b][i] + hp[3][b][i];
    }
    __syncthreads();

    // ================= layer 1: 64 -> 16 =================
    {
        const int o1 = lane & 15;
        const int ig = lane >> 4;          // 4 i-subgroups of 4
        const int i0 = 16 * iq + 4 * ig;

        auto ldw = [&](int i, v2f& w1, v2f& d1, float4& w2, v2f& d2, v2f& w3, float& b3v) {
            const int n = (i << 4) + o1;
            w1  = *(const v2f*)(B1 + 2 * n);
            d1  = *(const v2f*)(c1 + 2 * n);
            w2  = *(const float4*)(B2 + 4 * n);
            d2  = *(const v2f*)(c2 + 2 * n);
            w3  = *(const v2f*)(B3 + 2 * n);
            b3v = c3[n];
        };

        v2f acc2[16];
#pragma unroll
        for (int j = 0; j < 16; ++j) acc2[j] = zz;
        float bsum = 0.f;

        v2f w1, d1, d2, w3; float4 w2; float b3v;
        ldw(i0, w1, d1, w2, d2, w3, b3v);

#pragma unroll 1
        for (int ii = 0; ii < 4; ++ii) {
            const int i = i0 + ii;
            v2f nw1, nd1, nd2, nw3; float4 nw2; float nb3;
            ldw(i0 + ((ii + 1) & 3), nw1, nd1, nw2, nd2, nw3, nb3);

            const float4 hv0 = *(const float4*)&ht[i][boff];
            const float4 hv1 = *(const float4*)&ht[i][boff + 4];
            const float4 hv2 = *(const float4*)&ht[i][boff + 8];
            const float4 hv3 = *(const float4*)&ht[i][boff + 12];
            const float4 hv[4] = {hv0, hv1, hv2, hv3};

            bsum += b3v;
            const v2f c0  = {w2.x, w2.z};
            const v2f c1v = {w2.y, w2.w};
#pragma unroll
            for (int j = 0; j < 16; ++j) {
                const float hb = ((const float*)hv)[j];
                const v2f xd = {hb, hb};
                v2f m = __builtin_elementwise_fma(xd, w1, d1);
                m = __builtin_elementwise_max(m, zz);
                const v2f mm0 = {m.x, m.x};
                const v2f mm1 = {m.y, m.y};
                v2f tt = __builtin_elementwise_fma(c1v, mm1, d2);
                tt = __builtin_elementwise_fma(c0, mm0, tt);
                tt = __builtin_elementwise_max(tt, zz);
                acc2[j] = __builtin_elementwise_fma(w3, tt, acc2[j]);  // pk fma
            }
            w1 = nw1; d1 = nd1; w2 = nw2; d2 = nd2; w3 = nw3; b3v = nb3;
        }

        // reduce over ig (lanes 16 apart), write per-iq partial
#pragma unroll
        for (int j = 0; j < 16; ++j) {
            float v = acc2[j].x + acc2[j].y + bsum;
            v += __shfl_xor(v, 16, 64);
            v += __shfl_xor(v, 32, 64);
            if (ig == 0) op[iq][boff + j][o1] = v;
        }
    }
    __syncthreads();

    // ---- store: out = sum_q op[q], 512 floats, float4 coalesced ----
    if (t < 128) {
        const int f = t * 4;
        const float4 p0 = *(const float4*)(&op[0][0][0] + f);
        const float4 p1 = *(const float4*)(&op[1][0][0] + f);
        const float4 p2 = *(const float4*)(&op[2][0][0] + f);
        const float4 p3 = *(const float4*)(&op[3][0][0] + f);
        float4 r;
        r.x = p0.x + p1.x + p2.x + p3.x;
        r.y = p0.y + p1.y + p2.y + p3.y;
        r.z = p0.z + p1.z + p2.z + p3.z;
        r.w = p0.w + p1.w + p2.w + p3.w;
        *(float4*)(out + (long)bB0 * 16 + f) = r;
    }
}

extern "C" void kernel_launch(void* const* d_in, const int* in_sizes, int n_in,
                              void* d_out, int out_size, void* d_ws, size_t ws_size,
                              hipStream_t stream) {
    const float* x     = (const float*)d_in[0];
    const float* l0_W1 = (const float*)d_in[1];
    const float* l0_b1 = (const float*)d_in[2];
    const float* l0_W2 = (const float*)d_in[3];
    const float* l0_b2 = (const float*)d_in[4];
    const float* l0_W3 = (const float*)d_in[5];
    const float* l0_b3 = (const float*)d_in[6];
    const float* l1_W1 = (const float*)d_in[7];
    const float* l1_b1 = (const float*)d_in[8];
    const float* l1_W2 = (const float*)d_in[9];
    const float* l1_b2 = (const float*)d_in[10];
    const float* l1_W3 = (const float*)d_in[11];
    const float* l1_b3 = (const float*)d_in[12];

    float* outp = (float*)d_out;

    dim3 blk(512);
    dim3 grid(BATCH / TB);   // 512 blocks, 2 per CU
    hipLaunchKernelGGL(kan_fused6, grid, blk, 0, stream,
                       x,
                       l0_W1, l0_b1, l0_W2, l0_b2, l0_W3, l0_b3,
                       l1_W1, l1_b1, l1_W2, l1_b2, l1_W3, l1_b3,
                       outp);
}

// Round 8
// 104.284 us; speedup vs baseline: 1.4361x; 1.3488x over previous
//
#include <hip/hip_runtime.h>

// Fused MLPKAN, round 12 — scalar inner loop (evidence-driven).
// r11 instrumented ablation (REPEAT=3 on L0): VALUBusy 73% => L0 is
// VALU-ISSUE bound; measured ~19 VALU instrs per inner-j vs scalar minimum
// 12 (8 fma + 4 max). The v2f elementwise path scalarizes AND pays v_movs
// for mm0/mm1/c0/c1v repacking temps (~7 wasted ops/j = 35% of VALU).
// Fix: pure scalar compute — fmaf/fmaxf on float2/float4 MEMBERS (consecutive
// regs, no repack), zero movs. Structure otherwise r0 verbatim (iq x bh waves,
// acc[16], hp partials, combine, op partials; flat code — no lambdas returning
// structs: fused3/5's hidden +12-18KB LDS came from struct-copy codegen).
// LDS 59392 (= declared, verified clean in r11). Grid 512 = 2 blk/CU.
// Predict: kernel ~34 -> ~27us; dur_us ~103 -> ~96.

#define BATCH 16384
#define TB    32

__global__ __launch_bounds__(512, 4) void kan_fused7(
    const float* __restrict__ x,
    const float* __restrict__ A1, const float* __restrict__ a1,
    const float* __restrict__ A2, const float* __restrict__ a2,
    const float* __restrict__ A3, const float* __restrict__ a3,
    const float* __restrict__ B1, const float* __restrict__ c1,
    const float* __restrict__ B2, const float* __restrict__ c2,
    const float* __restrict__ B3, const float* __restrict__ c3,
    float* __restrict__ out)
{
    __shared__ float xs[64][36];        // x transposed: xs[i][b]
    __shared__ float hp[4][TB][64];     // layer0 partials per i-quarter
    __shared__ float ht[64][36];        // h transposed: ht[i][b]
    __shared__ float op[4][TB][16];     // layer1 partials per i-quarter

    const int t    = threadIdx.x;
    const int lane = t & 63;
    const int wave = t >> 6;            // 0..7
    const int iq   = wave & 3;          // i-quarter: [16*iq, 16*iq+16)
    const int bh   = wave >> 2;         // batch-half: [16*bh, 16*bh+16)
    const int bB0  = blockIdx.x * TB;

    // ---- stage x transposed: 2048 floats, 512 thr x float4 ----
    {
        const int k = t * 4;
        const float4 v = *(const float4*)(x + (long)bB0 * 64 + k);
        const int b = k >> 6, i = k & 63;
        xs[i][b] = v.x; xs[i + 1][b] = v.y; xs[i + 2][b] = v.z; xs[i + 3][b] = v.w;
    }
    __syncthreads();

    const int boff = 16 * bh;

    // ================= layer 0: 64 -> 64 =================
    {
        const int o  = lane;
        const int i0 = 16 * iq;

        float acc[16];
#pragma unroll
        for (int j = 0; j < 16; ++j) acc[j] = 0.f;
        float bsum = 0.f;

        // weights, flat vars, 1-deep prefetch (r0-proven)
        float2 w1, d1, d2, w3; float4 w2; float b3v;
        {
            const int n = (i0 << 6) + o;
            w1  = *(const float2*)(A1 + 2 * n);
            d1  = *(const float2*)(a1 + 2 * n);
            w2  = *(const float4*)(A2 + 4 * n);
            d2  = *(const float2*)(a2 + 2 * n);
            w3  = *(const float2*)(A3 + 2 * n);
            b3v = a3[n];
        }

#pragma unroll 1
        for (int ii = 0; ii < 16; ++ii) {
            const int i = i0 + ii;
            float2 nw1, nd1, nd2, nw3; float4 nw2; float nb3;
            {
                const int n = ((i0 + ((ii + 1) & 15)) << 6) + o;
                nw1 = *(const float2*)(A1 + 2 * n);
                nd1 = *(const float2*)(a1 + 2 * n);
                nw2 = *(const float4*)(A2 + 4 * n);
                nd2 = *(const float2*)(a2 + 2 * n);
                nw3 = *(const float2*)(A3 + 2 * n);
                nb3 = a3[n];
            }

            const float4 xv0 = *(const float4*)&xs[i][boff];          // ds b128
            const float4 xv1 = *(const float4*)&xs[i][boff + 4];
            const float4 xv2 = *(const float4*)&xs[i][boff + 8];
            const float4 xv3 = *(const float4*)&xs[i][boff + 12];
            const float4 xv[4] = {xv0, xv1, xv2, xv3};

            bsum += b3v;
#pragma unroll
            for (int j = 0; j < 16; ++j) {
                const float xb = ((const float*)xv)[j];
                float h1a = fmaf(xb, w1.x, d1.x); h1a = fmaxf(h1a, 0.f);
                float h1b = fmaf(xb, w1.y, d1.y); h1b = fmaxf(h1b, 0.f);
                float h2a = fmaf(w2.x, h1a, d2.x); h2a = fmaf(w2.y, h1b, h2a);
                h2a = fmaxf(h2a, 0.f);
                float h2b = fmaf(w2.z, h1a, d2.y); h2b = fmaf(w2.w, h1b, h2b);
                h2b = fmaxf(h2b, 0.f);
                acc[j] = fmaf(w3.x, h2a, fmaf(w3.y, h2b, acc[j]));
            }
            w1 = nw1; d1 = nd1; w2 = nw2; d2 = nd2; w3 = nw3; b3v = nb3;
        }

#pragma unroll
        for (int j = 0; j < 16; ++j)
            hp[iq][boff + j][o] = acc[j] + bsum;   // rows bank-aligned: 2-way, free
    }
    __syncthreads();

    // ---- combine i-quarters + transpose: ht[i][b] = sum_q hp[q][b][i] ----
    for (int k = t; k < TB * 64; k += 512) {
        const int b = k >> 6, i = k & 63;
        ht[i][b] = hp[0][b][i] + hp[1][b][i] + hp[2][b][i] + hp[3][b][i];
    }
    __syncthreads();

    // ================= layer 1: 64 -> 16 =================
    {
        const int o1 = lane & 15;
        const int ig = lane >> 4;          // 4 i-subgroups of 4
        const int i0 = 16 * iq + 4 * ig;

        float acc[16];
#pragma unroll
        for (int j = 0; j < 16; ++j) acc[j] = 0.f;
        float bsum = 0.f;

        float2 w1, d1, d2, w3; float4 w2; float b3v;
        {
            const int n = (i0 << 4) + o1;
            w1  = *(const float2*)(B1 + 2 * n);
            d1  = *(const float2*)(c1 + 2 * n);
            w2  = *(const float4*)(B2 + 4 * n);
            d2  = *(const float2*)(c2 + 2 * n);
            w3  = *(const float2*)(B3 + 2 * n);
            b3v = c3[n];
        }

#pragma unroll 1
        for (int ii = 0; ii < 4; ++ii) {
            const int i = i0 + ii;
            float2 nw1, nd1, nd2, nw3; float4 nw2; float nb3;
            {
                const int n = ((i0 + ((ii + 1) & 3)) << 4) + o1;
                nw1 = *(const float2*)(B1 + 2 * n);
                nd1 = *(const float2*)(c1 + 2 * n);
                nw2 = *(const float4*)(B2 + 4 * n);
                nd2 = *(const float2*)(c2 + 2 * n);
                nw3 = *(const float2*)(B3 + 2 * n);
                nb3 = c3[n];
            }

            const float4 hv0 = *(const float4*)&ht[i][boff];
            const float4 hv1 = *(const float4*)&ht[i][boff + 4];
            const float4 hv2 = *(const float4*)&ht[i][boff + 8];
            const float4 hv3 = *(const float4*)&ht[i][boff + 12];
            const float4 hv[4] = {hv0, hv1, hv2, hv3};

            bsum += b3v;
#pragma unroll
            for (int j = 0; j < 16; ++j) {
                const float hb = ((const float*)hv)[j];
                float h1a = fmaf(hb, w1.x, d1.x); h1a = fmaxf(h1a, 0.f);
                float h1b = fmaf(hb, w1.y, d1.y); h1b = fmaxf(h1b, 0.f);
                float h2a = fmaf(w2.x, h1a, d2.x); h2a = fmaf(w2.y, h1b, h2a);
                h2a = fmaxf(h2a, 0.f);
                float h2b = fmaf(w2.z, h1a, d2.y); h2b = fmaf(w2.w, h1b, h2b);
                h2b = fmaxf(h2b, 0.f);
                acc[j] = fmaf(w3.x, h2a, fmaf(w3.y, h2b, acc[j]));
            }
            w1 = nw1; d1 = nd1; w2 = nw2; d2 = nd2; w3 = nw3; b3v = nb3;
        }

        // reduce over ig (lanes 16 apart), write per-iq partial
#pragma unroll
        for (int j = 0; j < 16; ++j) {
            float v = acc[j] + bsum;
            v += __shfl_xor(v, 16, 64);
            v += __shfl_xor(v, 32, 64);
            if (ig == 0) op[iq][boff + j][o1] = v;
        }
    }
    __syncthreads();

    // ---- store: out = sum_q op[q], 512 floats, float4 coalesced ----
    if (t < 128) {
        const int f = t * 4;
        const float4 p0 = *(const float4*)(&op[0][0][0] + f);
        const float4 p1 = *(const float4*)(&op[1][0][0] + f);
        const float4 p2 = *(const float4*)(&op[2][0][0] + f);
        const float4 p3 = *(const float4*)(&op[3][0][0] + f);
        float4 r;
        r.x = p0.x + p1.x + p2.x + p3.x;
        r.y = p0.y + p1.y + p2.y + p3.y;
        r.z = p0.z + p1.z + p2.z + p3.z;
        r.w = p0.w + p1.w + p2.w + p3.w;
        *(float4*)(out + (long)bB0 * 16 + f) = r;
    }
}

extern "C" void kernel_launch(void* const* d_in, const int* in_sizes, int n_in,
                              void* d_out, int out_size, void* d_ws, size_t ws_size,
                              hipStream_t stream) {
    const float* x     = (const float*)d_in[0];
    const float* l0_W1 = (const float*)d_in[1];
    const float* l0_b1 = (const float*)d_in[2];
    const float* l0_W2 = (const float*)d_in[3];
    const float* l0_b2 = (const float*)d_in[4];
    const float* l0_W3 = (const float*)d_in[5];
    const float* l0_b3 = (const float*)d_in[6];
    const float* l1_W1 = (const float*)d_in[7];
    const float* l1_b1 = (const float*)d_in[8];
    const float* l1_W2 = (const float*)d_in[9];
    const float* l1_b2 = (const float*)d_in[10];
    const float* l1_W3 = (const float*)d_in[11];
    const float* l1_b3 = (const float*)d_in[12];

    float* outp = (float*)d_out;

    dim3 blk(512);
    dim3 grid(BATCH / TB);   // 512 blocks, 2 per CU
    hipLaunchKernelGGL(kan_fused7, grid, blk, 0, stream,
                       x,
                       l0_W1, l0_b1, l0_W2, l0_b2, l0_W3, l0_b3,
                       l1_W1, l1_b1, l1_W2, l1_b2, l1_W3, l1_b3,
                       outp);
}